// Round 7
// baseline (232.113 us; speedup 1.0000x reference)
//
#include <hip/hip_runtime.h>

#define NN 50000
#define EE 800000
#define DD 128
#define BN_EPS 1e-5f
#define XCONV_B 3125    // N*D/8/256
#define BIN_BLOCKS 200
#define BIN_EDGES 4000  // per block; 200*4000 == EE
#define NBUCK 3125      // 50000/16: 16-row buckets (exact)
#define BROWS 16
#define RCAP 64         // per-row CSR capacity (mean 16, +12 sigma; R5-validated)
#define NREP 32         // BN-stat replica count
#define GEMM_B 782      // ceil(NN/64) for gemm2
#define LDA 136         // padded LDS tile stride (bf16)
#define ZROW NN         // dummy zero row in xb (branchless gather padding)

typedef __attribute__((ext_vector_type(8))) short bf16x8;
typedef __attribute__((ext_vector_type(4))) float f32x4;
typedef __attribute__((ext_vector_type(8))) unsigned short u16x8;

__device__ inline unsigned short f2bf(float f) {  // RNE fp32 -> bf16
  unsigned int u = __float_as_uint(f);
  u = (u + 0x7fffu + ((u >> 16) & 1u)) >> 16;
  return (unsigned short)u;
}
__device__ inline float bf2f(unsigned short b) {
  return __uint_as_float(((unsigned int)b) << 16);
}
// clamped sorted-col fetch: OOB -> ZROW (zero row; adds 0.0 exactly)
__device__ inline int colof(const unsigned short* sc, int i, int e) {
  const unsigned short v = sc[i < e ? i : 0];
  return i < e ? (int)v : ZROW;
}

// ---------------------------------------------------------------------------
// R17. Lessons pinned: launch gap ~13-20us (R7-R9); __threadfence = L2 wb/inv
// storm (R12); in-kernel grid-sync fusion = ~40us idle convoys (R14/R15);
// shfl-addressed gather serializes on lgkmcnt (R15); gather invariant at
// ~50us across concurrency shapes, L2-resident slicing (R4 bound), and
// issue-before-consume double-buffering (R16) -> NOT request-rate/L2/
// concurrency-bound. Last un-isolated phase: the per-block LDS counting
// sort (~500 LDS atomics + 2-barrier scan per block ~ 10-15us kernel-wide).
// This round removes it: CSR-fixed binning (R5's k_binrow, proven) gives a
// row-sorted layout by construction; aggemm1's A1 phase becomes ONE
// contiguous 2KB csr->LDS copy + 16 count reads (no atomics, no scan).
// Gather core = R6's proven double-buffered branchless pipeline.
// Memory (d_out scratch, dead before k_bnrelu overwrites):
//   [0, 200004)     rcnt[NN] + done[1]
//   [4.0M,16.80M+256) xb = bf16(x) rows 0..50000 (row 50000 = zeros)
//   [16.80M+256, +6.4M) csr u16[NN*RCAP]
//   [23.28M,+32KB)  W1b; [23.36M,+32KB) W2b; [23.5M,+64KB) reps
// d_ws: h1b | h2b | scale2,shift2 tail. 5 dispatches.
// ---------------------------------------------------------------------------

// K0: fused prep — x->bf16 xb (+zero row), W1b, W2b, zero rcnt+done+reps
__global__ __launch_bounds__(256) void k_prep(const float* __restrict__ x,
                                              const float* __restrict__ W1,
                                              const float* __restrict__ W2,
                                              unsigned short* __restrict__ xb,
                                              unsigned short* __restrict__ W1b,
                                              unsigned short* __restrict__ W2b,
                                              int* __restrict__ rcnt,
                                              float* __restrict__ reps) {
  const int b = blockIdx.x;
  const int t = threadIdx.x;
  if (b < XCONV_B) {
    const int gid = b * 256 + t;
    const float4 v0 = ((const float4*)x)[gid * 2];
    const float4 v1 = ((const float4*)x)[gid * 2 + 1];
    ushort4 o0, o1;
    o0.x = f2bf(v0.x); o0.y = f2bf(v0.y); o0.z = f2bf(v0.z); o0.w = f2bf(v0.w);
    o1.x = f2bf(v1.x); o1.y = f2bf(v1.y); o1.z = f2bf(v1.z); o1.w = f2bf(v1.w);
    ((ushort4*)xb)[gid * 2] = o0;
    ((ushort4*)xb)[gid * 2 + 1] = o1;
    if (gid <= NN) rcnt[gid] = 0;  // includes done counter at [NN]
    if (gid < 4 * NREP * DD) reps[gid] = 0.0f;
    if (gid < 16) {  // dummy zero row xb[50000]
      const ushort4 z = {0, 0, 0, 0};
      ((ushort4*)(xb + (size_t)NN * DD))[gid * 2] = z;
      ((ushort4*)(xb + (size_t)NN * DD))[gid * 2 + 1] = z;
    }
  } else if (b < XCONV_B + 16) {
    const int gid = (b - XCONV_B) * 256 + t;
    const float4 v = ((const float4*)W1)[gid];
    ushort4 o;
    o.x = f2bf(v.x); o.y = f2bf(v.y); o.z = f2bf(v.z); o.w = f2bf(v.w);
    ((ushort4*)W1b)[gid] = o;
  } else {
    const int gid = (b - XCONV_B - 16) * 256 + t;
    const float4 v = ((const float4*)W2)[gid];
    ushort4 o;
    o.x = f2bf(v.x); o.y = f2bf(v.y); o.z = f2bf(v.z); o.w = f2bf(v.w);
    ((ushort4*)W2b)[gid] = o;
  }
}

// K1: CSR-fixed binning — one pass, row-sorted layout by construction (R5,
// proven: shipped and passed in R15 run). No LDS, global atomics spread over
// 50K counters.
__global__ __launch_bounds__(256) void k_binrow(const int* __restrict__ rows,
                                                const int* __restrict__ cols,
                                                int* __restrict__ rcnt,
                                                unsigned short* __restrict__ csr) {
  const int t = threadIdx.x;
  const int e0 = blockIdx.x * BIN_EDGES;
#pragma unroll
  for (int k = 0; k < 16; ++k) {
    const int li = t + k * 256;
    if (li < BIN_EDGES) {
      const int r = rows[e0 + li];
      const int c = cols[e0 + li];
      const int p = atomicAdd(&rcnt[r], 1);
      if (p < RCAP)  // statistically impossible overflow; memory-safety clamp
        csr[(size_t)r * RCAP + p] = (unsigned short)c;
    }
  }
}

// 8-load chunk issue (rows r0,r1; 4 edges each via sub-striding) + consume
#define ISSUE(P, Q, I0, I1)                                            \
  P##0 = *(const u16x8*)(xb + (size_t)colof(scols, (I0), end0) * DD + l16 * 8); \
  P##1 = *(const u16x8*)(xb + (size_t)colof(scols, (I0) + 4, end0) * DD + l16 * 8); \
  P##2 = *(const u16x8*)(xb + (size_t)colof(scols, (I0) + 8, end0) * DD + l16 * 8); \
  P##3 = *(const u16x8*)(xb + (size_t)colof(scols, (I0) + 12, end0) * DD + l16 * 8); \
  Q##0 = *(const u16x8*)(xb + (size_t)colof(scols, (I1), end1) * DD + l16 * 8); \
  Q##1 = *(const u16x8*)(xb + (size_t)colof(scols, (I1) + 4, end1) * DD + l16 * 8); \
  Q##2 = *(const u16x8*)(xb + (size_t)colof(scols, (I1) + 8, end1) * DD + l16 * 8); \
  Q##3 = *(const u16x8*)(xb + (size_t)colof(scols, (I1) + 12, end1) * DD + l16 * 8);

#define CONSUME(P, Q)                                                  \
  _Pragma("unroll") for (int j = 0; j < 8; ++j) {                      \
    a0[j] += (bf2f(P##0[j]) + bf2f(P##1[j])) +                         \
             (bf2f(P##2[j]) + bf2f(P##3[j]));                          \
    a1[j] += (bf2f(Q##0[j]) + bf2f(Q##1[j])) +                         \
             (bf2f(Q##2[j]) + bf2f(Q##3[j]));                          \
  }

// K2: FUSED aggregation + GEMM1. NO SORT: phase A1 is one contiguous 2KB
// csr->LDS copy + 16 count reads. Gather = R6's double-buffered branchless
// pipeline over fixed-stride CSR rows (roff[r] = r*64, end = r*64+cnt).
__global__ __launch_bounds__(128) void k_aggemm1(
    const unsigned short* __restrict__ xb, const float* __restrict__ eps,
    const int* __restrict__ rcnt, const unsigned short* __restrict__ csr,
    const unsigned short* __restrict__ W, const float* __restrict__ bias,
    unsigned short* __restrict__ outb, float* __restrict__ sum1r,
    float* __restrict__ sumsq1r) {
  __shared__ unsigned short scols[BROWS * RCAP];  // 2KB: this bucket's CSR rows
  __shared__ unsigned short sA[BROWS * LDA];      // 4.25KB padded A tile
  __shared__ int rl[BROWS];                       // per-row counts (clamped)
  const int t = threadIdx.x;
  const int bk = blockIdx.x;
  const int wv = t >> 6;       // 0..1
  const int lane = t & 63;
  const int sub = lane >> 4;   // 0..3
  const int l16 = lane & 15;

  // ---- phase A1': contiguous 2KB copy + counts (no atomics, no scan)
  *(u16x8*)(scols + t * 8) =
      *(const u16x8*)(csr + (size_t)bk * (BROWS * RCAP) + t * 8);
  if (t < BROWS) {
    const int c = rcnt[bk * BROWS + t];
    rl[t] = c < RCAP ? c : RCAP;
  }
  __syncthreads();

  // ---- phase A2: row-pair gather, double-buffered 16-edge chunks,
  // branchless full width (OOB edges -> ZROW, add exact 0.0)
  {
    const float s = 1.0f + eps[0];
#pragma unroll
    for (int rr = 0; rr < 4; ++rr) {
      const int r0 = wv + rr * 4;
      const int r1 = r0 + 2;
      float a0[8], a1[8];
#pragma unroll
      for (int j = 0; j < 8; ++j) { a0[j] = 0.f; a1[j] = 0.f; }
      if (sub < 2) {  // self rows: sub0 -> r0, sub1 -> r1, scaled by 1+eps
        const int selfrow = bk * BROWS + (sub == 0 ? r0 : r1);
        const u16x8 a = *(const u16x8*)(xb + (size_t)selfrow * DD + l16 * 8);
        if (sub == 0) {
#pragma unroll
          for (int j = 0; j < 8; ++j) a0[j] = s * bf2f(a[j]);
        } else {
#pragma unroll
          for (int j = 0; j < 8; ++j) a1[j] = s * bf2f(a[j]);
        }
      }
      const int n0 = rl[r0];
      const int n1 = rl[r1];
      const int end0 = r0 * RCAP + n0;
      const int end1 = r1 * RCAP + n1;
      int i0 = r0 * RCAP + sub;
      int i1 = r1 * RCAP + sub;
      int nb = (n0 > n1 ? n0 : n1);
      nb = (nb + 15) >> 4;  // wave-uniform chunk count (<= 4)
      u16x8 pa0, pa1, pa2, pa3, qa0, qa1, qa2, qa3;  // bank A
      u16x8 pb0, pb1, pb2, pb3, qb0, qb1, qb2, qb3;  // bank B
      if (nb > 0) {
        ISSUE(pa, qa, i0, i1);
        i0 += 16; i1 += 16;
        int k = nb - 1;
        while (k >= 2) {  // issue-next, consume-prev
          ISSUE(pb, qb, i0, i1);
          i0 += 16; i1 += 16;
          CONSUME(pa, qa);
          ISSUE(pa, qa, i0, i1);
          i0 += 16; i1 += 16;
          CONSUME(pb, qb);
          k -= 2;
        }
        if (k == 1) {
          ISSUE(pb, qb, i0, i1);
          CONSUME(pa, qa);
          CONSUME(pb, qb);
        } else {
          CONSUME(pa, qa);
        }
      }
#pragma unroll
      for (int j = 0; j < 8; ++j) {
        a0[j] += __shfl_xor(a0[j], 16);
        a0[j] += __shfl_xor(a0[j], 32);
        a1[j] += __shfl_xor(a1[j], 16);
        a1[j] += __shfl_xor(a1[j], 32);
      }
      if (sub < 2) {
        u16x8 o;
        if (sub == 0) {
#pragma unroll
          for (int j = 0; j < 8; ++j) o[j] = f2bf(a0[j]);
          *(u16x8*)(&sA[r0 * LDA + l16 * 8]) = o;
        } else {
#pragma unroll
          for (int j = 0; j < 8; ++j) o[j] = f2bf(a1[j]);
          *(u16x8*)(&sA[r1 * LDA + l16 * 8]) = o;
        }
      }
    }
  }
  __syncthreads();

  // ---- phase B: MFMA GEMM 16x128; wave wv owns cols [wv*64, +64)
  f32x4 acc[4];
#pragma unroll
  for (int nn = 0; nn < 4; ++nn) acc[nn] = (f32x4){0.f, 0.f, 0.f, 0.f};
#pragma unroll
  for (int kk = 0; kk < 4; ++kk) {
    const bf16x8 af = *(const bf16x8*)(&sA[l16 * LDA + kk * 32 + sub * 8]);
#pragma unroll
    for (int nn = 0; nn < 4; ++nn) {
      const bf16x8 bf = *(const bf16x8*)(
          W + (size_t)(wv * 64 + nn * 16 + l16) * DD + sub * 8 + kk * 32);
      acc[nn] = __builtin_amdgcn_mfma_f32_16x16x32_bf16(af, bf, acc[nn], 0, 0, 0);
    }
  }
  const int orow0 = bk * BROWS + sub * 4;
  const int rep = (bk & (NREP - 1)) * DD;
#pragma unroll
  for (int nn = 0; nn < 4; ++nn) {
    const int col = wv * 64 + nn * 16 + l16;
    const float bv = bias[col];
    float sv = 0.f, qv = 0.f;
#pragma unroll
    for (int r = 0; r < 4; ++r) {
      const float o = acc[nn][r] + bv;
      outb[(size_t)(orow0 + r) * DD + col] = f2bf(o);
      sv += o; qv += o * o;
    }
    sv += __shfl_xor(sv, 16); qv += __shfl_xor(qv, 16);
    sv += __shfl_xor(sv, 32); qv += __shfl_xor(qv, 32);
    if (sub == 0) {
      atomicAdd(&sum1r[rep + col], sv);
      atomicAdd(&sumsq1r[rep + col], qv);
    }
  }
}

// K3: GEMM2 with fused last-block BN2 collapse (R2, proven; fence-free)
__global__ __launch_bounds__(256) void k_gemm2(const unsigned short* __restrict__ A,
                                               const float* __restrict__ sum1r,
                                               const float* __restrict__ sumsq1r,
                                               const float* __restrict__ gamma,
                                               const float* __restrict__ beta,
                                               const unsigned short* __restrict__ W,
                                               const float* __restrict__ bias,
                                               unsigned short* __restrict__ outb,
                                               float* __restrict__ sum2r,
                                               float* __restrict__ sumsq2r,
                                               const float* __restrict__ gamma2,
                                               const float* __restrict__ beta2,
                                               float* __restrict__ scale2,
                                               float* __restrict__ shift2,
                                               int* __restrict__ done) {
  __shared__ float lsc[DD];
  __shared__ float lsh[DD];
  __shared__ float bsum[DD];
  __shared__ float bsq[DD];
  __shared__ int amlast;
  const int tid = threadIdx.x;
  const int wv = tid >> 6;
  const int lane = tid & 63;
  const int quad = lane >> 4;
  const int l16 = lane & 15;
  if (tid < DD) {
    float sm = 0.f, qm = 0.f;
#pragma unroll
    for (int r = 0; r < NREP; ++r) {
      sm += sum1r[r * DD + tid];
      qm += sumsq1r[r * DD + tid];
    }
    const float inv_n = 1.0f / (float)NN;
    const float mean = sm * inv_n;
    const float var = qm * inv_n - mean * mean;
    const float s = gamma[tid] * rsqrtf(var + BN_EPS);
    lsc[tid] = s;
    lsh[tid] = beta[tid] - mean * s;
    bsum[tid] = 0.f;
    bsq[tid] = 0.f;
  }
  __syncthreads();

  const int rowbase = blockIdx.x * 64 + wv * 16 + l16;
  const int arow = rowbase < NN ? rowbase : NN - 1;
  const unsigned short* aptr = A + (size_t)arow * DD + quad * 8;

  f32x4 acc[8];
#pragma unroll
  for (int n = 0; n < 8; ++n) acc[n] = (f32x4){0.f, 0.f, 0.f, 0.f};
#pragma unroll
  for (int kk = 0; kk < 4; ++kk) {
    const int kbase = kk * 32 + quad * 8;
    const u16x8 a = *(const u16x8*)(aptr + kk * 32);
    const float4 s0 = *(const float4*)&lsc[kbase];
    const float4 s1 = *(const float4*)&lsc[kbase + 4];
    const float4 h0 = *(const float4*)&lsh[kbase];
    const float4 h1 = *(const float4*)&lsh[kbase + 4];
    bf16x8 af;
    af[0] = (short)f2bf(fmaxf(fmaf(s0.x, bf2f(a[0]), h0.x), 0.f));
    af[1] = (short)f2bf(fmaxf(fmaf(s0.y, bf2f(a[1]), h0.y), 0.f));
    af[2] = (short)f2bf(fmaxf(fmaf(s0.z, bf2f(a[2]), h0.z), 0.f));
    af[3] = (short)f2bf(fmaxf(fmaf(s0.w, bf2f(a[3]), h0.w), 0.f));
    af[4] = (short)f2bf(fmaxf(fmaf(s1.x, bf2f(a[4]), h1.x), 0.f));
    af[5] = (short)f2bf(fmaxf(fmaf(s1.y, bf2f(a[5]), h1.y), 0.f));
    af[6] = (short)f2bf(fmaxf(fmaf(s1.z, bf2f(a[6]), h1.z), 0.f));
    af[7] = (short)f2bf(fmaxf(fmaf(s1.w, bf2f(a[7]), h1.w), 0.f));
#pragma unroll
    for (int n = 0; n < 8; ++n) {
      const bf16x8 bf =
          *(const bf16x8*)(W + (size_t)(n * 16 + l16) * DD + kbase);
      acc[n] = __builtin_amdgcn_mfma_f32_16x16x32_bf16(af, bf, acc[n], 0, 0, 0);
    }
  }
  const int orow0 = blockIdx.x * 64 + wv * 16 + quad * 4;
#pragma unroll
  for (int n = 0; n < 8; ++n) {
    const int col = n * 16 + l16;
    const float bv = bias[col];
    float sv = 0.f, qv = 0.f;
#pragma unroll
    for (int r = 0; r < 4; ++r) {
      const int row = orow0 + r;
      if (row < NN) {
        const float o = acc[n][r] + bv;
        outb[(size_t)row * DD + col] = f2bf(o);
        sv += o; qv += o * o;
      }
    }
    sv += __shfl_xor(sv, 16); qv += __shfl_xor(qv, 16);
    sv += __shfl_xor(sv, 32); qv += __shfl_xor(qv, 32);
    if (quad == 0) { atomicAdd(&bsum[col], sv); atomicAdd(&bsq[col], qv); }
  }
  __syncthreads();
  if (tid < DD) {
    const int rep = (blockIdx.x & (NREP - 1)) * DD;
    atomicAdd(&sum2r[rep + tid], bsum[tid]);
    atomicAdd(&sumsq2r[rep + tid], bsq[tid]);
  }
  // last-block BN2 collapse (fence-free: syncthreads drains vmcnt before
  // tid0's done-RMW; reader uses agent-scope atomic loads)
  __syncthreads();
  if (tid == 0) amlast = (atomicAdd(done, 1) == GEMM_B - 1) ? 1 : 0;
  __syncthreads();
  if (amlast) {
    if (tid < DD) {
      float sm = 0.f, qm = 0.f;
#pragma unroll
      for (int r = 0; r < NREP; ++r) {
        sm += __hip_atomic_load(&sum2r[r * DD + tid], __ATOMIC_RELAXED,
                                __HIP_MEMORY_SCOPE_AGENT);
        qm += __hip_atomic_load(&sumsq2r[r * DD + tid], __ATOMIC_RELAXED,
                                __HIP_MEMORY_SCOPE_AGENT);
      }
      const float inv_n = 1.0f / (float)NN;
      const float mean = sm * inv_n;
      const float var = qm * inv_n - mean * mean;
      const float sc = gamma2[tid] * rsqrtf(var + BN_EPS);
      scale2[tid] = sc;
      shift2[tid] = beta2[tid] - mean * sc;
    }
  }
}

// K4: final BN2 + ReLU -> fp32 out (proven)
__global__ __launch_bounds__(256) void k_bnrelu(const unsigned short* __restrict__ in,
                                                const float* __restrict__ scale,
                                                const float* __restrict__ shift,
                                                float* __restrict__ out) {
  __shared__ float lsc[DD];
  __shared__ float lsh[DD];
  const int t = threadIdx.x;
  if (t < DD) {
    lsc[t] = scale[t];
    lsh[t] = shift[t];
  }
  __syncthreads();
  const int gid = blockIdx.x * 256 + t;
  const int c = (gid & 15) * 8;
  const u16x8 a = ((const u16x8*)in)[gid];
  const float4 sc0 = *(const float4*)&lsc[c];
  const float4 sc1 = *(const float4*)&lsc[c + 4];
  const float4 sh0 = *(const float4*)&lsh[c];
  const float4 sh1 = *(const float4*)&lsh[c + 4];
  float4 o0, o1;
  o0.x = fmaxf(fmaf(sc0.x, bf2f(a[0]), sh0.x), 0.f);
  o0.y = fmaxf(fmaf(sc0.y, bf2f(a[1]), sh0.y), 0.f);
  o0.z = fmaxf(fmaf(sc0.z, bf2f(a[2]), sh0.z), 0.f);
  o0.w = fmaxf(fmaf(sc0.w, bf2f(a[3]), sh0.w), 0.f);
  o1.x = fmaxf(fmaf(sc1.x, bf2f(a[4]), sh1.x), 0.f);
  o1.y = fmaxf(fmaf(sc1.y, bf2f(a[5]), sh1.y), 0.f);
  o1.z = fmaxf(fmaf(sc1.z, bf2f(a[6]), sh1.z), 0.f);
  o1.w = fmaxf(fmaf(sc1.w, bf2f(a[7]), sh1.w), 0.f);
  ((float4*)out)[gid * 2] = o0;
  ((float4*)out)[gid * 2 + 1] = o1;
}

// ---------------------------------------------------------------------------
extern "C" void kernel_launch(void* const* d_in, const int* in_sizes, int n_in,
                              void* d_out, int out_size, void* d_ws, size_t ws_size,
                              hipStream_t stream) {
  const float* x = (const float*)d_in[0];
  const int* ei = (const int*)d_in[1];
  const float* eps = (const float*)d_in[2];
  const float* W1 = (const float*)d_in[3];
  const float* b1 = (const float*)d_in[4];
  const float* g1 = (const float*)d_in[5];
  const float* be1 = (const float*)d_in[6];
  const float* W2 = (const float*)d_in[7];
  const float* b2 = (const float*)d_in[8];
  const float* g2 = (const float*)d_in[9];
  const float* be2 = (const float*)d_in[10];
  float* out = (float*)d_out;

  const int* rows = ei;
  const int* cols = ei + EE;

  // d_out scratch (all dead before k_bnrelu writes d_out)
  int* rcnt = (int*)d_out;                                  // NN ints + done
  unsigned short* xb = (unsigned short*)d_out + 2000000;    // byte 4.0M (+zero row)
  unsigned short* csr = (unsigned short*)((char*)d_out + 16800256);  // 6.4MB
  unsigned short* W1b = (unsigned short*)d_out + 11640000;  // byte 23.28M
  unsigned short* W2b = (unsigned short*)d_out + 11680000;  // byte 23.36M
  float* reps = (float*)d_out + 5875000;                    // byte 23.5M, 64KB
  float* sum1r = reps;
  float* sumsq1r = reps + NREP * DD;
  float* sum2r = reps + 2 * NREP * DD;
  float* sumsq2r = reps + 3 * NREP * DD;
  int* done = rcnt + NN;

  unsigned short* h1b = (unsigned short*)d_ws;        // aggemm1 out
  unsigned short* h2b = h1b + (size_t)NN * DD;        // gemm2 out
  float* stats = (float*)(h1b + (size_t)2 * NN * DD); // 4KB tail of d_ws
  float* scale2 = stats + 0;
  float* shift2 = stats + 128;

  // 1. prep: x/W1/W2 -> bf16 (+zero row), zero rcnt+done+reps
  k_prep<<<XCONV_B + 32, 256, 0, stream>>>(x, W1, W2, xb, W1b, W2b, rcnt, reps);
  // 2. CSR-fixed binning (row-sorted in one pass, no LDS, no sort later)
  k_binrow<<<BIN_BLOCKS, 256, 0, stream>>>(rows, cols, rcnt, csr);
  // 3. FUSED gather (sort-free CSR) + GEMM1 -> h1b, BN1 stats
  k_aggemm1<<<NBUCK, 128, 0, stream>>>(xb, eps, rcnt, csr, W1b, b1, h1b,
                                       sum1r, sumsq1r);
  // 4. GEMM2 (BN1+ReLU on the fly) -> h2b; last block collapses BN2 stats
  k_gemm2<<<GEMM_B, 256, 0, stream>>>(h1b, sum1r, sumsq1r, g1, be1, W2b, b2,
                                      h2b, sum2r, sumsq2r, g2, be2,
                                      scale2, shift2, done);
  // 5. final BN2+ReLU -> fp32 out
  k_bnrelu<<<(NN * DD / 8) / 256, 256, 0, stream>>>(h2b, scale2, shift2, out);
}

// Round 8
// 212.743 us; speedup vs baseline: 1.0910x; 1.0910x over previous
//
#include <hip/hip_runtime.h>

#define NN 50000
#define EE 800000
#define DD 128
#define BN_EPS 1e-5f
#define XCONV_B 3125    // N*D/8/256
#define BIN_BLOCKS 200
#define BIN_EDGES 4000  // per block; 200*4000 == EE
#define NBUCK 3125      // 50000/16: 16-row buckets (exact)
#define BROWS 16
#define BCAP 512        // bucket capacity (mean 256, +16 sigma headroom)
#define NREP 32         // BN-stat replica count
#define GEMM2B 391      // ceil(NN/128) for 128-row gemm2
#define LDA 136         // padded LDS tile stride (bf16)
#define ZROW NN         // dummy zero row in xb (branchless gather padding)

typedef __attribute__((ext_vector_type(8))) short bf16x8;
typedef __attribute__((ext_vector_type(4))) float f32x4;
typedef __attribute__((ext_vector_type(8))) unsigned short u16x8;

__device__ inline unsigned short f2bf(float f) {  // RNE fp32 -> bf16
  unsigned int u = __float_as_uint(f);
  u = (u + 0x7fffu + ((u >> 16) & 1u)) >> 16;
  return (unsigned short)u;
}
__device__ inline float bf2f(unsigned short b) {
  return __uint_as_float(((unsigned int)b) << 16);
}
// clamped sorted-col fetch: OOB -> ZROW (zero row; adds 0.0 exactly)
__device__ inline int colof(const unsigned short* sc, int i, int e) {
  const unsigned short v = sc[i < e ? i : 0];
  return i < e ? (int)v : ZROW;
}

// ---------------------------------------------------------------------------
// R18 = consolidation. Lessons pinned: launch gap ~13-20us (R7-R9);
// __threadfence = L2 wb/inv storm (R12); in-kernel grid-sync fusion = ~40us
// idle convoys (R14/R15); shfl-addressed gather lgkmcnt-serializes (R15);
// CSR sort-removal was a regression — sort exonerated (R17); gather best =
// R6 exact (50.4us): 16-row buckets, 2-wave blocks, in-block sort, double-
// buffered branchless pipeline. VALUBusy x dur ~ 16-17us fixed VALU work;
// rest is unhidden latency at HW-pinned ~5-7 waves/CU.
// This round: (1) aggemm1 = R6 + wave-uniform guards skipping fully-dummy
// ISSUE/CONSUME chunk-halves (~25% of A2 work was ZROW padding);
// (2) prep+bin0 fused into one dispatch (bcur zeroing -> hipMemsetAsync);
// (3) gemm2 widened to 128 rows/block (391 blocks, acc[2][8]).
// Memory (d_out scratch, dead before k_bnrelu overwrites):
//   [0,12.5KB)      bcur[NBUCK] + done[1]          (zeroed by memsetAsync)
//   [4.0M,16.80M+256) xb = bf16(x) rows 0..50000 (row 50000 = zeros)
//   [16.80M+256, +6.4M) bbuf u32[NBUCK*BCAP] packed (row&15)<<16|col
//   [23.28M,+32KB)  W1b; [23.36M,+32KB) W2b; [23.5M,+64KB) reps
// d_ws: h1b | h2b | scale2,shift2 tail. 4 kernel dispatches + 1 memset.
// ---------------------------------------------------------------------------

// K0: fused prep + binning. Blocks [0,XCONV_B): x->bf16 (+zero row, reps);
// [XCONV_B,+16): W1; [+16,+32): W2; [+32,+32+BIN_BLOCKS): edge binning.
// bcur is pre-zeroed by hipMemsetAsync (bin blocks may run before/with
// x-blocks; no cross-branch dependency).
__global__ __launch_bounds__(256) void k_prepbin(
    const float* __restrict__ x, const float* __restrict__ W1,
    const float* __restrict__ W2, const int* __restrict__ rows,
    const int* __restrict__ cols, unsigned short* __restrict__ xb,
    unsigned short* __restrict__ W1b, unsigned short* __restrict__ W2b,
    int* __restrict__ bcur, unsigned int* __restrict__ bbuf,
    float* __restrict__ reps) {
  __shared__ int hist[NBUCK];   // 12.5KB (bin branch only)
  __shared__ int lbase[NBUCK];  // 12.5KB
  const int b = blockIdx.x;
  const int t = threadIdx.x;
  if (b < XCONV_B) {
    const int gid = b * 256 + t;
    const float4 v0 = ((const float4*)x)[gid * 2];
    const float4 v1 = ((const float4*)x)[gid * 2 + 1];
    ushort4 o0, o1;
    o0.x = f2bf(v0.x); o0.y = f2bf(v0.y); o0.z = f2bf(v0.z); o0.w = f2bf(v0.w);
    o1.x = f2bf(v1.x); o1.y = f2bf(v1.y); o1.z = f2bf(v1.z); o1.w = f2bf(v1.w);
    ((ushort4*)xb)[gid * 2] = o0;
    ((ushort4*)xb)[gid * 2 + 1] = o1;
    if (gid < 4 * NREP * DD) reps[gid] = 0.0f;
    if (gid < 16) {  // dummy zero row xb[50000]
      const ushort4 z = {0, 0, 0, 0};
      ((ushort4*)(xb + (size_t)NN * DD))[gid * 2] = z;
      ((ushort4*)(xb + (size_t)NN * DD))[gid * 2 + 1] = z;
    }
  } else if (b < XCONV_B + 16) {
    const int gid = (b - XCONV_B) * 256 + t;
    const float4 v = ((const float4*)W1)[gid];
    ushort4 o;
    o.x = f2bf(v.x); o.y = f2bf(v.y); o.z = f2bf(v.z); o.w = f2bf(v.w);
    ((ushort4*)W1b)[gid] = o;
  } else if (b < XCONV_B + 32) {
    const int gid = (b - XCONV_B - 16) * 256 + t;
    const float4 v = ((const float4*)W2)[gid];
    ushort4 o;
    o.x = f2bf(v.x); o.y = f2bf(v.y); o.z = f2bf(v.z); o.w = f2bf(v.w);
    ((ushort4*)W2b)[gid] = o;
  } else {
    // ---- binning (R6 k_bin0 body, proven)
    const int bb = b - XCONV_B - 32;
    for (int i = t; i < NBUCK; i += 256) hist[i] = 0;
    __syncthreads();
    const int e0 = bb * BIN_EDGES;
    int er[16], ec[16];
#pragma unroll
    for (int i = 0; i < 16; ++i) {
      const int idx = t + i * 256;
      if (idx < BIN_EDGES) {
        er[i] = rows[e0 + idx];
        ec[i] = cols[e0 + idx];
        atomicAdd(&hist[er[i] >> 4], 1);
      }
    }
    __syncthreads();
    for (int i = t; i < NBUCK; i += 256) {
      const int c = hist[i];
      lbase[i] = (c > 0) ? atomicAdd(&bcur[i], c) : 0;
      hist[i] = 0;
    }
    __syncthreads();
#pragma unroll
    for (int i = 0; i < 16; ++i) {
      const int idx = t + i * 256;
      if (idx < BIN_EDGES) {
        const int bk = er[i] >> 4;
        const int lp = lbase[bk] + atomicAdd(&hist[bk], 1);
        if (lp < BCAP)
          bbuf[(size_t)bk * BCAP + lp] =
              ((unsigned)(er[i] & 15) << 16) | (unsigned)ec[i];
      }
    }
  }
}

// 4-load half-chunk issue / consume (one row, 16 edges via sub-striding)
#define ISSUE_P(P, I)                                                  \
  P##0 = *(const u16x8*)(xb + (size_t)colof(scols, (I), end0) * DD + l16 * 8); \
  P##1 = *(const u16x8*)(xb + (size_t)colof(scols, (I) + 4, end0) * DD + l16 * 8); \
  P##2 = *(const u16x8*)(xb + (size_t)colof(scols, (I) + 8, end0) * DD + l16 * 8); \
  P##3 = *(const u16x8*)(xb + (size_t)colof(scols, (I) + 12, end0) * DD + l16 * 8);
#define ISSUE_Q(Q, I)                                                  \
  Q##0 = *(const u16x8*)(xb + (size_t)colof(scols, (I), end1) * DD + l16 * 8); \
  Q##1 = *(const u16x8*)(xb + (size_t)colof(scols, (I) + 4, end1) * DD + l16 * 8); \
  Q##2 = *(const u16x8*)(xb + (size_t)colof(scols, (I) + 8, end1) * DD + l16 * 8); \
  Q##3 = *(const u16x8*)(xb + (size_t)colof(scols, (I) + 12, end1) * DD + l16 * 8);
#define CONS_P(P)                                                      \
  _Pragma("unroll") for (int j = 0; j < 8; ++j)                        \
      a0[j] += (bf2f(P##0[j]) + bf2f(P##1[j])) +                       \
               (bf2f(P##2[j]) + bf2f(P##3[j]));
#define CONS_Q(Q)                                                      \
  _Pragma("unroll") for (int j = 0; j < 8; ++j)                        \
      a1[j] += (bf2f(Q##0[j]) + bf2f(Q##1[j])) +                       \
               (bf2f(Q##2[j]) + bf2f(Q##3[j]));

// K1: FUSED per-bucket sort + gather + GEMM1 — R6 structure (best: 50.4us)
// with wave-uniform dummy-chunk guards (off<n0 / off<n1 are uniform).
__global__ __launch_bounds__(128) void k_aggemm1(
    const unsigned short* __restrict__ xb, const float* __restrict__ eps,
    const int* __restrict__ bcnt, const unsigned int* __restrict__ bbuf,
    const unsigned short* __restrict__ W, const float* __restrict__ bias,
    unsigned short* __restrict__ outb, float* __restrict__ sum1r,
    float* __restrict__ sumsq1r) {
  __shared__ unsigned short scols[BCAP];      // 1KB sorted col ids
  __shared__ unsigned short sA[BROWS * LDA];  // 4.25KB padded A tile
  __shared__ int rcnt[BROWS];
  __shared__ int roff[BROWS + 1];
  const int t = threadIdx.x;
  const int bk = blockIdx.x;
  const int wv = t >> 6;       // 0..1
  const int lane = t & 63;
  const int sub = lane >> 4;   // 0..3
  const int l16 = lane & 15;

  int n = bcnt[bk];
  n = n < BCAP ? n : BCAP;
  if (t < BROWS) rcnt[t] = 0;
  __syncthreads();

  // ---- phase A1: load bucket entries + per-row count + counting sort
  unsigned int ent[4];
  int nl = 0;
  for (int i = t; i < n; i += 128) {
    const unsigned int e = bbuf[(size_t)bk * BCAP + i];
    ent[nl++] = e;
    atomicAdd(&rcnt[e >> 16], 1);
  }
  __syncthreads();
  if (t < BROWS) {
    int v = rcnt[t];
#pragma unroll
    for (int off = 1; off < BROWS; off <<= 1) {
      const int u = __shfl_up(v, off);
      if (lane >= off) v += u;
    }
    roff[t] = v - rcnt[t];
    if (t == BROWS - 1) roff[BROWS] = v;
    rcnt[t] = 0;
  }
  __syncthreads();
  for (int i = 0; i < nl; ++i) {
    const int r = ent[i] >> 16;
    const int pos = roff[r] + atomicAdd(&rcnt[r], 1);
    scols[pos] = (unsigned short)(ent[i] & 0xffffu);
  }
  __syncthreads();

  // ---- phase A2: row-pair gather, double-buffered, dummy-guarded
  {
    const float s = 1.0f + eps[0];
#pragma unroll
    for (int rr = 0; rr < 4; ++rr) {
      const int r0 = wv + rr * 4;
      const int r1 = r0 + 2;
      float a0[8], a1[8];
#pragma unroll
      for (int j = 0; j < 8; ++j) { a0[j] = 0.f; a1[j] = 0.f; }
      if (sub < 2) {  // self rows: sub0 -> r0, sub1 -> r1, scaled by 1+eps
        const int selfrow = bk * BROWS + (sub == 0 ? r0 : r1);
        const u16x8 a = *(const u16x8*)(xb + (size_t)selfrow * DD + l16 * 8);
        if (sub == 0) {
#pragma unroll
          for (int j = 0; j < 8; ++j) a0[j] = s * bf2f(a[j]);
        } else {
#pragma unroll
          for (int j = 0; j < 8; ++j) a1[j] = s * bf2f(a[j]);
        }
      }
      const int end0 = roff[r0 + 1];
      const int end1 = roff[r1 + 1];
      const int n0 = end0 - roff[r0];
      const int n1 = end1 - roff[r1];
      int i0 = roff[r0] + sub;
      int i1 = roff[r1] + sub;
      int nb = (n0 > n1 ? n0 : n1);
      nb = (nb + 15) >> 4;  // wave-uniform chunk count
      u16x8 pa0, pa1, pa2, pa3, qa0, qa1, qa2, qa3;  // bank A
      u16x8 pb0, pb1, pb2, pb3, qb0, qb1, qb2, qb3;  // bank B
      if (nb > 0) {
        int off = 0, aoff = 0, boff = 0;
        if (off < n0) { ISSUE_P(pa, i0); }
        if (off < n1) { ISSUE_Q(qa, i1); }
        aoff = off; off += 16; i0 += 16; i1 += 16;
        int k = nb - 1;
        while (k >= 2) {  // issue-next, consume-prev (guarded halves)
          if (off < n0) { ISSUE_P(pb, i0); }
          if (off < n1) { ISSUE_Q(qb, i1); }
          boff = off; off += 16; i0 += 16; i1 += 16;
          if (aoff < n0) { CONS_P(pa); }
          if (aoff < n1) { CONS_Q(qa); }
          if (off < n0) { ISSUE_P(pa, i0); }
          if (off < n1) { ISSUE_Q(qa, i1); }
          aoff = off; off += 16; i0 += 16; i1 += 16;
          if (boff < n0) { CONS_P(pb); }
          if (boff < n1) { CONS_Q(qb); }
          k -= 2;
        }
        if (k == 1) {
          if (off < n0) { ISSUE_P(pb, i0); }
          if (off < n1) { ISSUE_Q(qb, i1); }
          boff = off;
          if (aoff < n0) { CONS_P(pa); }
          if (aoff < n1) { CONS_Q(qa); }
          if (boff < n0) { CONS_P(pb); }
          if (boff < n1) { CONS_Q(qb); }
        } else {
          if (aoff < n0) { CONS_P(pa); }
          if (aoff < n1) { CONS_Q(qa); }
        }
      }
#pragma unroll
      for (int j = 0; j < 8; ++j) {
        a0[j] += __shfl_xor(a0[j], 16);
        a0[j] += __shfl_xor(a0[j], 32);
        a1[j] += __shfl_xor(a1[j], 16);
        a1[j] += __shfl_xor(a1[j], 32);
      }
      if (sub < 2) {
        u16x8 o;
        if (sub == 0) {
#pragma unroll
          for (int j = 0; j < 8; ++j) o[j] = f2bf(a0[j]);
          *(u16x8*)(&sA[r0 * LDA + l16 * 8]) = o;
        } else {
#pragma unroll
          for (int j = 0; j < 8; ++j) o[j] = f2bf(a1[j]);
          *(u16x8*)(&sA[r1 * LDA + l16 * 8]) = o;
        }
      }
    }
  }
  __syncthreads();

  // ---- phase B: MFMA GEMM 16x128; wave wv owns cols [wv*64, +64)
  f32x4 acc[4];
#pragma unroll
  for (int nn = 0; nn < 4; ++nn) acc[nn] = (f32x4){0.f, 0.f, 0.f, 0.f};
#pragma unroll
  for (int kk = 0; kk < 4; ++kk) {
    const bf16x8 af = *(const bf16x8*)(&sA[l16 * LDA + kk * 32 + sub * 8]);
#pragma unroll
    for (int nn = 0; nn < 4; ++nn) {
      const bf16x8 bf = *(const bf16x8*)(
          W + (size_t)(wv * 64 + nn * 16 + l16) * DD + sub * 8 + kk * 32);
      acc[nn] = __builtin_amdgcn_mfma_f32_16x16x32_bf16(af, bf, acc[nn], 0, 0, 0);
    }
  }
  const int orow0 = bk * BROWS + sub * 4;
  const int rep = (bk & (NREP - 1)) * DD;
#pragma unroll
  for (int nn = 0; nn < 4; ++nn) {
    const int col = wv * 64 + nn * 16 + l16;
    const float bv = bias[col];
    float sv = 0.f, qv = 0.f;
#pragma unroll
    for (int r = 0; r < 4; ++r) {
      const float o = acc[nn][r] + bv;
      outb[(size_t)(orow0 + r) * DD + col] = f2bf(o);
      sv += o; qv += o * o;
    }
    sv += __shfl_xor(sv, 16); qv += __shfl_xor(qv, 16);
    sv += __shfl_xor(sv, 32); qv += __shfl_xor(qv, 32);
    if (sub == 0) {
      atomicAdd(&sum1r[rep + col], sv);
      atomicAdd(&sumsq1r[rep + col], qv);
    }
  }
}

// K2: GEMM2, 128 rows/block (391 blocks), fused last-block BN2 collapse
// (fence-free R12 protocol).
__global__ __launch_bounds__(256) void k_gemm2(const unsigned short* __restrict__ A,
                                               const float* __restrict__ sum1r,
                                               const float* __restrict__ sumsq1r,
                                               const float* __restrict__ gamma,
                                               const float* __restrict__ beta,
                                               const unsigned short* __restrict__ W,
                                               const float* __restrict__ bias,
                                               unsigned short* __restrict__ outb,
                                               float* __restrict__ sum2r,
                                               float* __restrict__ sumsq2r,
                                               const float* __restrict__ gamma2,
                                               const float* __restrict__ beta2,
                                               float* __restrict__ scale2,
                                               float* __restrict__ shift2,
                                               int* __restrict__ done) {
  __shared__ float lsc[DD];
  __shared__ float lsh[DD];
  __shared__ float bsum[DD];
  __shared__ float bsq[DD];
  __shared__ int amlast;
  const int tid = threadIdx.x;
  const int wv = tid >> 6;
  const int lane = tid & 63;
  const int quad = lane >> 4;
  const int l16 = lane & 15;
  if (tid < DD) {
    float sm = 0.f, qm = 0.f;
#pragma unroll
    for (int r = 0; r < NREP; ++r) {
      sm += sum1r[r * DD + tid];
      qm += sumsq1r[r * DD + tid];
    }
    const float inv_n = 1.0f / (float)NN;
    const float mean = sm * inv_n;
    const float var = qm * inv_n - mean * mean;
    const float s = gamma[tid] * rsqrtf(var + BN_EPS);
    lsc[tid] = s;
    lsh[tid] = beta[tid] - mean * s;
    bsum[tid] = 0.f;
    bsq[tid] = 0.f;
  }
  __syncthreads();

  const int rb0 = blockIdx.x * 128 + wv * 32 + l16;
  const int ar0 = rb0 < NN ? rb0 : NN - 1;
  const int ar1 = (rb0 + 16) < NN ? (rb0 + 16) : NN - 1;
  const unsigned short* ap0 = A + (size_t)ar0 * DD + quad * 8;
  const unsigned short* ap1 = A + (size_t)ar1 * DD + quad * 8;

  f32x4 acc[2][8];
#pragma unroll
  for (int m = 0; m < 2; ++m)
#pragma unroll
    for (int n = 0; n < 8; ++n) acc[m][n] = (f32x4){0.f, 0.f, 0.f, 0.f};
#pragma unroll
  for (int kk = 0; kk < 4; ++kk) {
    const int kbase = kk * 32 + quad * 8;
    const u16x8 x0 = *(const u16x8*)(ap0 + kk * 32);
    const u16x8 x1 = *(const u16x8*)(ap1 + kk * 32);
    const float4 s0 = *(const float4*)&lsc[kbase];
    const float4 s1 = *(const float4*)&lsc[kbase + 4];
    const float4 h0 = *(const float4*)&lsh[kbase];
    const float4 h1 = *(const float4*)&lsh[kbase + 4];
    bf16x8 af0, af1;
    af0[0] = (short)f2bf(fmaxf(fmaf(s0.x, bf2f(x0[0]), h0.x), 0.f));
    af0[1] = (short)f2bf(fmaxf(fmaf(s0.y, bf2f(x0[1]), h0.y), 0.f));
    af0[2] = (short)f2bf(fmaxf(fmaf(s0.z, bf2f(x0[2]), h0.z), 0.f));
    af0[3] = (short)f2bf(fmaxf(fmaf(s0.w, bf2f(x0[3]), h0.w), 0.f));
    af0[4] = (short)f2bf(fmaxf(fmaf(s1.x, bf2f(x0[4]), h1.x), 0.f));
    af0[5] = (short)f2bf(fmaxf(fmaf(s1.y, bf2f(x0[5]), h1.y), 0.f));
    af0[6] = (short)f2bf(fmaxf(fmaf(s1.z, bf2f(x0[6]), h1.z), 0.f));
    af0[7] = (short)f2bf(fmaxf(fmaf(s1.w, bf2f(x0[7]), h1.w), 0.f));
    af1[0] = (short)f2bf(fmaxf(fmaf(s0.x, bf2f(x1[0]), h0.x), 0.f));
    af1[1] = (short)f2bf(fmaxf(fmaf(s0.y, bf2f(x1[1]), h0.y), 0.f));
    af1[2] = (short)f2bf(fmaxf(fmaf(s0.z, bf2f(x1[2]), h0.z), 0.f));
    af1[3] = (short)f2bf(fmaxf(fmaf(s0.w, bf2f(x1[3]), h0.w), 0.f));
    af1[4] = (short)f2bf(fmaxf(fmaf(s1.x, bf2f(x1[4]), h1.x), 0.f));
    af1[5] = (short)f2bf(fmaxf(fmaf(s1.y, bf2f(x1[5]), h1.y), 0.f));
    af1[6] = (short)f2bf(fmaxf(fmaf(s1.z, bf2f(x1[6]), h1.z), 0.f));
    af1[7] = (short)f2bf(fmaxf(fmaf(s1.w, bf2f(x1[7]), h1.w), 0.f));
#pragma unroll
    for (int n = 0; n < 8; ++n) {
      const bf16x8 bf =
          *(const bf16x8*)(W + (size_t)(n * 16 + l16) * DD + kbase);
      acc[0][n] = __builtin_amdgcn_mfma_f32_16x16x32_bf16(af0, bf, acc[0][n], 0, 0, 0);
      acc[1][n] = __builtin_amdgcn_mfma_f32_16x16x32_bf16(af1, bf, acc[1][n], 0, 0, 0);
    }
  }
  const int orow0 = blockIdx.x * 128 + wv * 32 + quad * 4;
#pragma unroll
  for (int n = 0; n < 8; ++n) {
    const int col = n * 16 + l16;
    const float bv = bias[col];
    float sv = 0.f, qv = 0.f;
#pragma unroll
    for (int m = 0; m < 2; ++m)
#pragma unroll
      for (int r = 0; r < 4; ++r) {
        const int row = orow0 + m * 16 + r;
        if (row < NN) {
          const float o = acc[m][n][r] + bv;
          outb[(size_t)row * DD + col] = f2bf(o);
          sv += o; qv += o * o;
        }
      }
    sv += __shfl_xor(sv, 16); qv += __shfl_xor(qv, 16);
    sv += __shfl_xor(sv, 32); qv += __shfl_xor(qv, 32);
    if (quad == 0) { atomicAdd(&bsum[col], sv); atomicAdd(&bsq[col], qv); }
  }
  __syncthreads();
  if (tid < DD) {
    const int rep = (blockIdx.x & (NREP - 1)) * DD;
    atomicAdd(&sum2r[rep + tid], bsum[tid]);
    atomicAdd(&sumsq2r[rep + tid], bsq[tid]);
  }
  // last-block BN2 collapse (fence-free: syncthreads drains vmcnt before
  // tid0's done-RMW; reader uses agent-scope atomic loads)
  __syncthreads();
  if (tid == 0) amlast = (atomicAdd(done, 1) == GEMM2B - 1) ? 1 : 0;
  __syncthreads();
  if (amlast) {
    if (tid < DD) {
      float sm = 0.f, qm = 0.f;
#pragma unroll
      for (int r = 0; r < NREP; ++r) {
        sm += __hip_atomic_load(&sum2r[r * DD + tid], __ATOMIC_RELAXED,
                                __HIP_MEMORY_SCOPE_AGENT);
        qm += __hip_atomic_load(&sumsq2r[r * DD + tid], __ATOMIC_RELAXED,
                                __HIP_MEMORY_SCOPE_AGENT);
      }
      const float inv_n = 1.0f / (float)NN;
      const float mean = sm * inv_n;
      const float var = qm * inv_n - mean * mean;
      const float sc = gamma2[tid] * rsqrtf(var + BN_EPS);
      scale2[tid] = sc;
      shift2[tid] = beta2[tid] - mean * sc;
    }
  }
}

// K3: final BN2 + ReLU -> fp32 out (proven)
__global__ __launch_bounds__(256) void k_bnrelu(const unsigned short* __restrict__ in,
                                                const float* __restrict__ scale,
                                                const float* __restrict__ shift,
                                                float* __restrict__ out) {
  __shared__ float lsc[DD];
  __shared__ float lsh[DD];
  const int t = threadIdx.x;
  if (t < DD) {
    lsc[t] = scale[t];
    lsh[t] = shift[t];
  }
  __syncthreads();
  const int gid = blockIdx.x * 256 + t;
  const int c = (gid & 15) * 8;
  const u16x8 a = ((const u16x8*)in)[gid];
  const float4 sc0 = *(const float4*)&lsc[c];
  const float4 sc1 = *(const float4*)&lsc[c + 4];
  const float4 sh0 = *(const float4*)&lsh[c];
  const float4 sh1 = *(const float4*)&lsh[c + 4];
  float4 o0, o1;
  o0.x = fmaxf(fmaf(sc0.x, bf2f(a[0]), sh0.x), 0.f);
  o0.y = fmaxf(fmaf(sc0.y, bf2f(a[1]), sh0.y), 0.f);
  o0.z = fmaxf(fmaf(sc0.z, bf2f(a[2]), sh0.z), 0.f);
  o0.w = fmaxf(fmaf(sc0.w, bf2f(a[3]), sh0.w), 0.f);
  o1.x = fmaxf(fmaf(sc1.x, bf2f(a[4]), sh1.x), 0.f);
  o1.y = fmaxf(fmaf(sc1.y, bf2f(a[5]), sh1.y), 0.f);
  o1.z = fmaxf(fmaf(sc1.z, bf2f(a[6]), sh1.z), 0.f);
  o1.w = fmaxf(fmaf(sc1.w, bf2f(a[7]), sh1.w), 0.f);
  ((float4*)out)[gid * 2] = o0;
  ((float4*)out)[gid * 2 + 1] = o1;
}

// ---------------------------------------------------------------------------
extern "C" void kernel_launch(void* const* d_in, const int* in_sizes, int n_in,
                              void* d_out, int out_size, void* d_ws, size_t ws_size,
                              hipStream_t stream) {
  const float* x = (const float*)d_in[0];
  const int* ei = (const int*)d_in[1];
  const float* eps = (const float*)d_in[2];
  const float* W1 = (const float*)d_in[3];
  const float* b1 = (const float*)d_in[4];
  const float* g1 = (const float*)d_in[5];
  const float* be1 = (const float*)d_in[6];
  const float* W2 = (const float*)d_in[7];
  const float* b2 = (const float*)d_in[8];
  const float* g2 = (const float*)d_in[9];
  const float* be2 = (const float*)d_in[10];
  float* out = (float*)d_out;

  const int* rows = ei;
  const int* cols = ei + EE;

  // d_out scratch (all dead before k_bnrelu writes d_out)
  int* bcur = (int*)d_out;                                  // NBUCK ints + done
  unsigned short* xb = (unsigned short*)d_out + 2000000;    // byte 4.0M (+zero row)
  unsigned int* bbuf = (unsigned int*)((char*)d_out + 16800256);  // 6.4MB
  unsigned short* W1b = (unsigned short*)d_out + 11640000;  // byte 23.28M
  unsigned short* W2b = (unsigned short*)d_out + 11680000;  // byte 23.36M
  float* reps = (float*)d_out + 5875000;                    // byte 23.5M, 64KB
  float* sum1r = reps;
  float* sumsq1r = reps + NREP * DD;
  float* sum2r = reps + 2 * NREP * DD;
  float* sumsq2r = reps + 3 * NREP * DD;
  int* done = bcur + NBUCK;

  unsigned short* h1b = (unsigned short*)d_ws;        // aggemm1 out
  unsigned short* h2b = h1b + (size_t)NN * DD;        // gemm2 out
  float* stats = (float*)(h1b + (size_t)2 * NN * DD); // 4KB tail of d_ws
  float* scale2 = stats + 0;
  float* shift2 = stats + 128;

  // 0. zero bucket cursors + done counter (enables prep+bin fusion)
  hipMemsetAsync(bcur, 0, (NBUCK + 1) * sizeof(int), stream);
  // 1. fused prep + binning (one dispatch; saves a ~13us launch gap)
  k_prepbin<<<XCONV_B + 32 + BIN_BLOCKS, 256, 0, stream>>>(
      x, W1, W2, rows, cols, xb, W1b, W2b, bcur, bbuf, reps);
  // 2. FUSED sort + dummy-guarded double-buffered gather + GEMM1
  k_aggemm1<<<NBUCK, 128, 0, stream>>>(xb, eps, bcur, bbuf, W1b, b1, h1b,
                                       sum1r, sumsq1r);
  // 3. GEMM2 128-row blocks (BN1+ReLU on the fly); last block collapses BN2
  k_gemm2<<<GEMM2B, 256, 0, stream>>>(h1b, sum1r, sumsq1r, g1, be1, W2b, b2,
                                      h2b, sum2r, sumsq2r, g2, be2,
                                      scale2, shift2, done);
  // 4. final BN2+ReLU -> fp32 out
  k_bnrelu<<<(NN * DD / 8) / 256, 256, 0, stream>>>(h2b, scale2, shift2, out);
}